// Round 1
// baseline (374.871 us; speedup 1.0000x reference)
//
#include <hip/hip_runtime.h>

// TBConv2d: BN(inference) -> ternary{-1,0,1} -> conv3x3(p=1) -> +bias -> ReLU
// B=16, Cin=32, H=W=256, Cout=32. Fully fused single kernel, MFMA bf16 path.

#define B_    16
#define CIN   32
#define H_    256
#define W_    256
#define COUT  32
#define TH    8
#define TW    32
#define HALO_H 10      // TH+2
#define HALO_W 34      // TW+2
#define NPIX   340     // HALO_H*HALO_W
#define XPAIRS 17      // HALO_W/2
#define YXP    170     // HALO_H*XPAIRS

typedef __bf16 bf16x8 __attribute__((ext_vector_type(8)));
typedef float  f32x4  __attribute__((ext_vector_type(4)));

union FragCast { int4 i; bf16x8 b; };

__device__ __forceinline__ unsigned short f2bf(float f) {
    union { float f; unsigned int u; } c; c.f = f;
    unsigned int u = c.u;
    unsigned int r = u + 0x7FFFu + ((u >> 16) & 1u);   // RNE
    return (unsigned short)(r >> 16);
}

__launch_bounds__(256, 3)
__global__ void tbconv_kernel(const float* __restrict__ x,
                              const float* __restrict__ bn_gamma,
                              const float* __restrict__ bn_beta,
                              const float* __restrict__ bn_mean,
                              const float* __restrict__ bn_var,
                              const float* __restrict__ conv_w,
                              const float* __restrict__ conv_b,
                              float* __restrict__ out)
{
    // sQ: quantized halo tile, [pixel][ci] bf16, 16B chunks XOR-swizzled
    __shared__ __align__(16) unsigned short sQ[NPIX * 32];     // 21760 B
    // sB: phase1/2 = transpose staging sQx[ci][y*17+xp]; then = sW[tap][co][ci]
    __shared__ __align__(16) unsigned int   sB[32 * YXP];      // 21760 B
    __shared__ float sScale[32], sShift[32];

    const int tid = threadIdx.x;
    const int bx  = blockIdx.x;
    const int wt  = bx & 7;
    const int ht  = (bx >> 3) & 31;
    const int b   = bx >> 8;
    const int y0  = ht * TH;
    const int x0  = wt * TW;

    // BN per-channel constants (exact numpy op order: only sign(xh) matters)
    if (tid < 32) {
        float s = __fdiv_rn(bn_gamma[tid], __fsqrt_rn(__fadd_rn(bn_var[tid], 1e-4f)));
        sScale[tid] = s;
        sShift[tid] = __fsub_rn(bn_beta[tid], __fmul_rn(bn_mean[tid], s));
    }
    __syncthreads();

    // ---- Phase 1: load halo, BN + ternary quantize, pack x-pairs ----
    // item i = ci*170 + y*17 + xp  (xp fastest -> coalesced-ish global reads)
    for (int i = tid; i < 32 * YXP; i += 256) {
        int xp   = i % XPAIRS;
        int rest = i / XPAIRS;
        int y    = rest % HALO_H;
        int ci   = rest / HALO_H;
        int yg   = y0 - 1 + y;
        int xg   = x0 - 1 + 2 * xp;
        float sc = sScale[ci], sh = sShift[ci];
        unsigned int packed = 0;
        if (yg >= 0 && yg < H_) {
            const float* row = x + ((size_t)(b * CIN + ci) * H_ + yg) * W_;
            #pragma unroll
            for (int e = 0; e < 2; ++e) {
                int xe = xg + e;
                unsigned int q = 0;
                if (xe >= 0 && xe < W_) {
                    float xv = row[xe];
                    float xh = __fadd_rn(__fmul_rn(xv, sc), sh);
                    // torch semantics @thr=0: x<= -0 -> -1 (0 maps to -1), else x>=0 -> +1
                    q = (xh <= -0.0f) ? 0xBF80u : ((xh >= 0.0f) ? 0x3F80u : 0u);
                }
                packed |= q << (16 * e);
            }
        }
        sB[i] = packed;   // addr == i -> conflict-free consecutive dwords
    }
    __syncthreads();

    // ---- Phase 2: transpose to sQ[pixel][ci], chunk-swizzled b128 writes ----
    for (int i = tid; i < 4 * YXP; i += 256) {
        int cig = i & 3;           // ci chunk of 8
        int yxp = i >> 2;
        int y   = yxp / XPAIRS;
        int xp  = yxp - y * XPAIRS;
        unsigned int w[8];
        #pragma unroll
        for (int r = 0; r < 8; ++r)
            w[r] = sB[(8 * cig + r) * YXP + yxp];   // 2-way bank alias = free
        int p0 = y * HALO_W + 2 * xp;
        int lo[4], hi[4];
        #pragma unroll
        for (int k = 0; k < 4; ++k) {
            lo[k] = (int)((w[2*k] & 0xFFFFu) | ((w[2*k+1] & 0xFFFFu) << 16));
            hi[k] = (int)((w[2*k] >> 16)     | ((w[2*k+1] >> 16)     << 16));
        }
        int idx0 = p0 * 4 + cig;       idx0 ^= (idx0 >> 3) & 7;
        int idx1 = (p0 + 1) * 4 + cig; idx1 ^= (idx1 >> 3) & 7;
        *(int4*)((char*)sQ + idx0 * 16) = make_int4(lo[0], lo[1], lo[2], lo[3]);
        *(int4*)((char*)sQ + idx1 * 16) = make_int4(hi[0], hi[1], hi[2], hi[3]);
    }
    __syncthreads();

    // ---- Stage weights into sB as sW[tap][co][ci] bf16 (L2-cached source) ----
    for (int j = tid; j < 4608; j += 256) {
        int ci2 = (j & 15) * 2;
        int co  = (j >> 4) & 31;
        int t   = j >> 9;
        float w0 = conv_w[(co * 32 + ci2)     * 9 + t];
        float w1 = conv_w[(co * 32 + ci2 + 1) * 9 + t];
        sB[j] = (unsigned int)f2bf(w0) | ((unsigned int)f2bf(w1) << 16);
    }
    __syncthreads();

    // ---- MFMA main loop ----
    const unsigned short* sW = (const unsigned short*)sB;  // [tap][co][ci]
    const int wave = tid >> 6;
    const int lane = tid & 63;
    const int quad = lane >> 4;
    const int n    = lane & 15;
    const int pwave = wave * 64;

    f32x4 acc[2][4];
    #pragma unroll
    for (int ct = 0; ct < 2; ++ct)
        #pragma unroll
        for (int pt = 0; pt < 4; ++pt)
            acc[ct][pt] = (f32x4){0.f, 0.f, 0.f, 0.f};

    #pragma unroll
    for (int kh = 0; kh < 3; ++kh) {
        #pragma unroll
        for (int kw = 0; kw < 3; ++kw) {
            const int t = kh * 3 + kw;
            // A frags (weights): A[m=co=n][k=ci=quad*8+j]
            FragCast a0, a1;
            a0.i = *(const int4*)((const char*)sW + (((t * 32 + n)      * 32) + quad * 8) * 2);
            a1.i = *(const int4*)((const char*)sW + (((t * 32 + 16 + n) * 32) + quad * 8) * 2);
            #pragma unroll
            for (int pt = 0; pt < 4; ++pt) {
                int p_out  = pwave + pt * 16 + n;     // B col n = output pixel
                int py     = p_out >> 5, px = p_out & 31;
                int p_halo = (py + kh) * HALO_W + (px + kw);
                int idx    = p_halo * 4 + quad;
                idx ^= (idx >> 3) & 7;
                FragCast bq;
                bq.i = *(const int4*)((const char*)sQ + idx * 16);
                acc[0][pt] = __builtin_amdgcn_mfma_f32_16x16x32_bf16(a0.b, bq.b, acc[0][pt], 0, 0, 0);
                acc[1][pt] = __builtin_amdgcn_mfma_f32_16x16x32_bf16(a1.b, bq.b, acc[1][pt], 0, 0, 0);
            }
        }
    }

    // ---- Epilogue: +bias, ReLU, coalesced stores (C/D: row=co=quad*4+r, col=pixel=n) ----
    #pragma unroll
    for (int ct = 0; ct < 2; ++ct) {
        #pragma unroll
        for (int r = 0; r < 4; ++r) {
            const int co = ct * 16 + quad * 4 + r;
            const float bias = conv_b[co];
            #pragma unroll
            for (int pt = 0; pt < 4; ++pt) {
                int p_out = pwave + pt * 16 + n;
                int py = p_out >> 5, px = p_out & 31;
                float v = fmaxf(acc[ct][pt][r] + bias, 0.0f);
                out[((size_t)(b * COUT + co) << 16) | (unsigned)((y0 + py) << 8) | (unsigned)(x0 + px)] = v;
            }
        }
    }
}

extern "C" void kernel_launch(void* const* d_in, const int* in_sizes, int n_in,
                              void* d_out, int out_size, void* d_ws, size_t ws_size,
                              hipStream_t stream) {
    const float* x     = (const float*)d_in[0];
    const float* gamma = (const float*)d_in[1];
    const float* beta  = (const float*)d_in[2];
    const float* mean  = (const float*)d_in[3];
    const float* var   = (const float*)d_in[4];
    const float* w     = (const float*)d_in[5];
    const float* bias  = (const float*)d_in[6];
    float* o = (float*)d_out;

    dim3 grid(B_ * (H_ / TH) * (W_ / TW));   // 16*32*8 = 4096
    dim3 block(256);
    hipLaunchKernelGGL(tbconv_kernel, grid, block, 0, stream,
                       x, gamma, beta, mean, var, w, bias, o);
}

// Round 2
// 272.483 us; speedup vs baseline: 1.3758x; 1.3758x over previous
//
#include <hip/hip_runtime.h>

// TBConv2d: BN -> ternary{-1,0,1} -> conv3x3(p=1) -> +bias -> ReLU
// Streaming row-pipeline: block = 32-wide x-strip x 32-row y-chunk.
// 4-row LDS ring of quantized activations [pix][ci] bf16; weights in regs.

#define B_    16
#define H_    256
#define W_    256
#define SW    32
#define YC    32
#define ROWB  2304          // 36 pixel slots (34 real + 2 trash) * 64 B
#define NITEM 576           // 32 ci * 18 float2-pairs per row

typedef __bf16 bf16x8 __attribute__((ext_vector_type(8)));
typedef float  f32x4  __attribute__((ext_vector_type(4)));
union FragCast { int4 i; bf16x8 b; };

__device__ __forceinline__ unsigned short f2bf(float f) {
    union { float f; unsigned u; } c; c.f = f;
    unsigned u = c.u;
    u += 0x7FFFu + ((u >> 16) & 1u);      // RNE
    return (unsigned short)(u >> 16);
}

// torch semantics @thr=0: x <= -0 -> -1 (catches 0), else x >= 0 -> +1, NaN -> 0
__device__ __forceinline__ unsigned short quant1(float v, float sc, float sh) {
    float xh = __fadd_rn(__fmul_rn(v, sc), sh);   // exact numpy op order, no FMA
    return (xh <= 0.0f) ? (unsigned short)0xBF80u
         : ((xh >= 0.0f) ? (unsigned short)0x3F80u : (unsigned short)0u);
}

__launch_bounds__(256, 4)
__global__ void tbconv_kernel(const float* __restrict__ x,
                              const float* __restrict__ bn_g,
                              const float* __restrict__ bn_b,
                              const float* __restrict__ bn_m,
                              const float* __restrict__ bn_v,
                              const float* __restrict__ conv_w,
                              const float* __restrict__ conv_b,
                              float* __restrict__ out)
{
    __shared__ __align__(16) unsigned char sQ[4 * ROWB];   // 9216 B ring
    __shared__ __align__(16) unsigned int  sW[4608];       // 18432 B weights bf16 [tap][co][ci]
    __shared__ float sScale[32], sShift[32];

    const int tid = threadIdx.x;
    const int bx  = blockIdx.x;
    const int strip = bx & 7;
    const int yc    = (bx >> 3) & 7;
    const int b     = bx >> 6;
    const int x0 = strip * SW;
    const int y0 = yc * YC;          // multiple of 4 -> ring slots fold to constants

    if (tid < 32) {
        float s = __fdiv_rn(bn_g[tid], __fsqrt_rn(__fadd_rn(bn_v[tid], 1e-4f)));
        sScale[tid] = s;
        sShift[tid] = __fsub_rn(bn_b[tid], __fmul_rn(bn_m[tid], s));
    }
    // stage weights: sW dword j = [t][co][ci-pair]
    for (int j = tid; j < 4608; j += 256) {
        int cp = j & 15, co = (j >> 4) & 31, t = j >> 9;
        float w0 = conv_w[(co * 32 + 2 * cp)     * 9 + t];
        float w1 = conv_w[(co * 32 + 2 * cp + 1) * 9 + t];
        sW[j] = (unsigned)f2bf(w0) | ((unsigned)f2bf(w1) << 16);
    }
    __syncthreads();

    // ---- per-thread loader items: i = (ci, pr); aligned float2 at gx = x0-2+2*pr ----
    const float* lp[3];
    int   lw0[3], lw1[3];
    float lsc[3], lsh[3];
    bool  lxok[3];
    const bool lv2 = (tid < 64);     // third item exists only for wave 0
    #pragma unroll
    for (int j = 0; j < 3; ++j) {
        int i = tid + 256 * j; if (i >= NITEM) i = 0;
        int ci = i / 18, pr = i - 18 * ci;
        int gx = x0 - 2 + 2 * pr;
        bool xok = (gx >= 0) && (gx < W_);       // pairs are all-valid or all-invalid
        int gxc = (gx < 0) ? 0 : ((gx > 254) ? 254 : gx);
        lp[j]   = x + (((size_t)(b * 32 + ci)) << 16) + gxc;
        lxok[j] = xok;
        int hx0 = 2 * pr - 1, hx1 = 2 * pr;      // halo pixel coords of the 2 elements
        int hc0 = (hx0 < 0)  ? 34 : hx0;         // trash slots 34/35 (never read)
        int hc1 = (hx1 > 33) ? 35 : hx1;
        int q = ci >> 3, cl = ci & 7;
        // chunk-level XOR swizzle: phys chunk = hx*4 + (cioct ^ ((hx>>1)&3))
        lw0[j] = ((hc0 * 4 + (q ^ ((hc0 >> 1) & 3))) << 4) + cl * 2;
        lw1[j] = ((hc1 * 4 + (q ^ ((hc1 >> 1) & 3))) << 4) + cl * 2;
        lsc[j] = sScale[ci]; lsh[j] = sShift[ci];
    }

    // ---- wave/tile setup: wave = (ct = co-half, xh = x-half) ----
    const int lane = tid & 63, wave = tid >> 6;
    const int quad = lane >> 4, n = lane & 15;
    const int ct = wave >> 1, xh = wave & 1;
    const int xl = xh * 16 + n;

    // persistent A-frags: A[m=co=ct*16+n][k=ci=quad*8+j] per tap
    FragCast fA[9];
    #pragma unroll
    for (int t = 0; t < 9; ++t)
        fA[t].i = *(const int4*)((const char*)sW + ((t * 32 + ct * 16 + n) * 32 + quad * 8) * 2);

    // per-lane B-frag LDS offsets (y-invariant; slot becomes an immediate)
    int dsoff[3];
    #pragma unroll
    for (int kw = 0; kw < 3; ++kw) {
        int hx = xl + kw;
        dsoff[kw] = (hx * 4 + (quad ^ ((hx >> 1) & 3))) << 4;
    }

    float  bias[4];
    size_t obase[4];
    #pragma unroll
    for (int r = 0; r < 4; ++r) {
        int co = ct * 16 + quad * 4 + r;
        bias[r]  = conv_b[co];
        obase[r] = (((size_t)(b * 32 + co)) << 16) + ((size_t)y0 << 8) + (x0 + xl);
    }

    float2 v[3];
    auto load_row = [&](int gy) {
        bool yok = ((unsigned)gy < (unsigned)H_);
        #pragma unroll
        for (int j = 0; j < 3; ++j) {
            v[j] = make_float2(0.f, 0.f);
            if (yok && (j < 2 || lv2))
                v[j] = *(const float2*)(lp[j] + (gy << 8));
        }
    };
    auto scatter = [&](int gy, int slot) {
        bool yok = ((unsigned)gy < (unsigned)H_);
        char* rowp = (char*)sQ + slot * ROWB;
        #pragma unroll
        for (int j = 0; j < 3; ++j) {
            if (j < 2 || lv2) {
                unsigned short q0 = 0, q1 = 0;
                if (yok && lxok[j]) {
                    q0 = quant1(v[j].x, lsc[j], lsh[j]);
                    q1 = quant1(v[j].y, lsc[j], lsh[j]);
                }
                *(unsigned short*)(rowp + lw0[j]) = q0;   // padding/out-of-range -> 0
                *(unsigned short*)(rowp + lw1[j]) = q1;
            }
        }
    };

    // ---- prologue: quantize rows y0-1..y0+1, prefetch y0+2 ----
    load_row(y0 - 1); scatter(y0 - 1, 3);
    load_row(y0);     scatter(y0,     0);
    load_row(y0 + 1); scatter(y0 + 1, 1);
    load_row(y0 + 2);
    __syncthreads();

    // ---- main loop: 1 output row per step, 1 barrier per step ----
    for (int t8 = 0; t8 < 8; ++t8) {
        #pragma unroll
        for (int u = 0; u < 4; ++u) {
            const int yy = t8 * 4 + u;
            const int y  = y0 + yy;

            f32x4 acc[3];
            #pragma unroll
            for (int kh = 0; kh < 3; ++kh) {
                const int sb = ((u + 3 + kh) & 3) * ROWB;    // slot(y-1+kh), compile-time
                f32x4 a = {0.f, 0.f, 0.f, 0.f};
                #pragma unroll
                for (int kw = 0; kw < 3; ++kw) {
                    FragCast fB;
                    fB.i = *(const int4*)((const char*)sQ + sb + dsoff[kw]);
                    a = __builtin_amdgcn_mfma_f32_16x16x32_bf16(fA[kh * 3 + kw].b, fB.b, a, 0, 0, 0);
                }
                acc[kh] = a;
            }

            if (yy <= 30) scatter(y + 2, (u + 2) & 3);   // uniform guard
            __syncthreads();

            // stores after the barrier: they drain at the NEXT barrier, a full iter away
            #pragma unroll
            for (int r = 0; r < 4; ++r) {
                float s = __fadd_rn(__fadd_rn(acc[0][r], acc[1][r]),
                                    __fadd_rn(acc[2][r], bias[r]));
                out[obase[r] + (yy << 8)] = fmaxf(s, 0.f);
            }
            if (yy <= 29) load_row(y + 3);               // prefetch, consumed next iter
        }
    }
}

extern "C" void kernel_launch(void* const* d_in, const int* in_sizes, int n_in,
                              void* d_out, int out_size, void* d_ws, size_t ws_size,
                              hipStream_t stream) {
    const float* x     = (const float*)d_in[0];
    const float* gamma = (const float*)d_in[1];
    const float* beta  = (const float*)d_in[2];
    const float* mean  = (const float*)d_in[3];
    const float* var   = (const float*)d_in[4];
    const float* w     = (const float*)d_in[5];
    const float* bias  = (const float*)d_in[6];
    float* o = (float*)d_out;

    dim3 grid(B_ * 8 * 8);    // 16 batches x 8 x-strips x 8 y-chunks = 1024
    dim3 block(256);
    hipLaunchKernelGGL(tbconv_kernel, grid, block, 0, stream,
                       x, gamma, beta, mean, var, w, bias, o);
}